// Round 1
// baseline (286.392 us; speedup 1.0000x reference)
//
#include <hip/hip_runtime.h>
#include <cfloat>
#include <climits>

// Retriever: cosine-sim top-5 over 100k knowledge vectors + gather.
// query [64,768] f32, knowledge_embed [100000,768] f32, knowledge_full [100000,32] i32
// out = concat( topk_knowledge [64,5,32] (written as f32 values, exact ints),
//               topk_embed     [64,5,768] f32 )

#define BQ 64
#define DD 768
#define NK 100000
#define LK 32
#define K_TOP 5
#define BN 64
#define BKS 32
#define NTILES ((NK + BN - 1) / BN)   // 1563

__global__ __launch_bounds__(256) void qnorm_kernel(const float* __restrict__ q,
                                                    float* __restrict__ qn) {
    int b = blockIdx.x, t = threadIdx.x;
    float s = 0.f;
    for (int k = t; k < DD; k += 256) { float v = q[b * DD + k]; s += v * v; }
    for (int off = 32; off > 0; off >>= 1) s += __shfl_down(s, off, 64);
    __shared__ float red[4];
    if ((t & 63) == 0) red[t >> 6] = s;
    __syncthreads();
    if (t == 0) qn[b] = sqrtf(red[0] + red[1] + red[2] + red[3]);
}

// One block computes sims for all 64 queries x 64 knowledge vectors, plus
// the k-norms (fused, so knowledge_embed is read exactly once), then emits
// per-block top-5 (val,idx) per query.
__global__ __launch_bounds__(256) void sims_topk_kernel(
    const float* __restrict__ q, const float* __restrict__ ke,
    const float* __restrict__ qn,
    float* __restrict__ pvals, int* __restrict__ pidx)
{
    __shared__ float As[BKS][BQ];        // A tile, [k][q]
    __shared__ float Bs[BKS][BN];        // B tile, [k][n]
    __shared__ float S[BQ][BN + 1];      // sims tile (+1 pad: conflict-free row scan)
    __shared__ float ksq4[4][BN];
    __shared__ float kn[BN];

    const int t = threadIdx.x;
    const int n0 = blockIdx.x * BN;
    const int tx = t & 15, ty = t >> 4;   // 16x16 threads, 4x4 micro-tile
    const int lrow = t >> 2, kg = t & 3;  // staging: row + float4 group
    const int nl = t & 63, kq = t >> 6;   // norm accumulation split

    float acc[4][4];
#pragma unroll
    for (int i = 0; i < 4; ++i)
#pragma unroll
        for (int j = 0; j < 4; ++j) acc[i][j] = 0.f;
    float bsq = 0.f;

    const bool bvalid = (n0 + lrow) < NK;
    const float* qrowp = q + lrow * DD;
    const float* krowp = ke + (size_t)(n0 + lrow) * DD;

    for (int kt = 0; kt < DD; kt += BKS) {
        // ---- stage A (query) and B (knowledge) tiles into LDS ----
        float4 a0 = *(const float4*)(qrowp + kt + kg * 4);
        float4 a1 = *(const float4*)(qrowp + kt + 16 + kg * 4);
        float4 b0 = make_float4(0.f, 0.f, 0.f, 0.f), b1 = b0;
        if (bvalid) {
            b0 = *(const float4*)(krowp + kt + kg * 4);
            b1 = *(const float4*)(krowp + kt + 16 + kg * 4);
        }
        As[kg * 4 + 0][lrow] = a0.x;  As[kg * 4 + 1][lrow] = a0.y;
        As[kg * 4 + 2][lrow] = a0.z;  As[kg * 4 + 3][lrow] = a0.w;
        As[16 + kg * 4 + 0][lrow] = a1.x;  As[16 + kg * 4 + 1][lrow] = a1.y;
        As[16 + kg * 4 + 2][lrow] = a1.z;  As[16 + kg * 4 + 3][lrow] = a1.w;
        Bs[kg * 4 + 0][lrow] = b0.x;  Bs[kg * 4 + 1][lrow] = b0.y;
        Bs[kg * 4 + 2][lrow] = b0.z;  Bs[kg * 4 + 3][lrow] = b0.w;
        Bs[16 + kg * 4 + 0][lrow] = b1.x;  Bs[16 + kg * 4 + 1][lrow] = b1.y;
        Bs[16 + kg * 4 + 2][lrow] = b1.z;  Bs[16 + kg * 4 + 3][lrow] = b1.w;
        __syncthreads();

        // ---- compute ----
#pragma unroll
        for (int kk = 0; kk < BKS; ++kk) {
            float4 av = *(const float4*)&As[kk][ty * 4];
            float4 bv = *(const float4*)&Bs[kk][tx * 4];
            float a_[4] = {av.x, av.y, av.z, av.w};
            float b_[4] = {bv.x, bv.y, bv.z, bv.w};
#pragma unroll
            for (int i = 0; i < 4; ++i)
#pragma unroll
                for (int j = 0; j < 4; ++j)
                    acc[i][j] = fmaf(a_[i], b_[j], acc[i][j]);
        }
        // fused k-norm partial (reads Bs inside the synced region)
#pragma unroll
        for (int j = 0; j < 8; ++j) { float x = Bs[kq * 8 + j][nl]; bsq += x * x; }
        __syncthreads();
    }

    // ---- finish k-norms ----
    ksq4[kq][nl] = bsq;
    __syncthreads();
    if (t < BN) kn[t] = sqrtf(ksq4[0][t] + ksq4[1][t] + ksq4[2][t] + ksq4[3][t]);
    __syncthreads();

    // ---- sims -> LDS tile ----
    float qn4[4];
#pragma unroll
    for (int i = 0; i < 4; ++i) qn4[i] = qn[ty * 4 + i];
#pragma unroll
    for (int i = 0; i < 4; ++i)
#pragma unroll
        for (int j = 0; j < 4; ++j)
            S[ty * 4 + i][tx * 4 + j] =
                acc[i][j] / fmaxf(qn4[i] * kn[tx * 4 + j], 1e-8f);
    __syncthreads();

    // ---- per-block top-5 per query (thread t handles query t) ----
    if (t < BQ) {
        float v5[K_TOP]; int i5[K_TOP];
#pragma unroll
        for (int m = 0; m < K_TOP; ++m) { v5[m] = -FLT_MAX; i5[m] = INT_MAX; }
        for (int j = 0; j < BN; ++j) {
            int n = n0 + j;
            if (n >= NK) break;
            float v = S[t][j];
            if (v > v5[K_TOP - 1]) {   // strict >: equal values keep lower index
                int p = K_TOP - 1;
                while (p > 0 && v > v5[p - 1]) {
                    v5[p] = v5[p - 1]; i5[p] = i5[p - 1]; --p;
                }
                v5[p] = v; i5[p] = n;
            }
        }
        int base = (blockIdx.x * BQ + t) * K_TOP;
#pragma unroll
        for (int m = 0; m < K_TOP; ++m) { pvals[base + m] = v5[m]; pidx[base + m] = i5[m]; }
    }
}

__device__ __forceinline__ void insert5(float v, int n, float* v5, int* i5) {
    if (v > v5[4] || (v == v5[4] && n < i5[4])) {
        int p = 4;
        while (p > 0 && (v > v5[p - 1] || (v == v5[p - 1] && n < i5[p - 1]))) {
            v5[p] = v5[p - 1]; i5[p] = i5[p - 1]; --p;
        }
        v5[p] = v; i5[p] = n;
    }
}

// One block per query: merge 1563*5 partial candidates -> final top-5,
// then gather knowledge rows (as f32 values) and embed rows directly to out.
__global__ __launch_bounds__(256) void reduce_gather_kernel(
    const float* __restrict__ pvals, const int* __restrict__ pidx,
    const float* __restrict__ ke, const int* __restrict__ kf,
    float* __restrict__ out)
{
    const int qi = blockIdx.x, t = threadIdx.x;
    __shared__ float sv[256 * K_TOP];
    __shared__ int   si[256 * K_TOP];
    __shared__ int   fi[K_TOP];

    float v5[K_TOP]; int i5[K_TOP];
#pragma unroll
    for (int m = 0; m < K_TOP; ++m) { v5[m] = -FLT_MAX; i5[m] = INT_MAX; }

    const int NC = NTILES * K_TOP;   // 7815
    for (int c = t; c < NC; c += 256) {
        int blk = c / K_TOP, m = c - blk * K_TOP;
        int off = (blk * BQ + qi) * K_TOP + m;
        insert5(pvals[off], pidx[off], v5, i5);
    }
#pragma unroll
    for (int m = 0; m < K_TOP; ++m) { sv[t * K_TOP + m] = v5[m]; si[t * K_TOP + m] = i5[m]; }
    __syncthreads();

    if (t < 32) {
#pragma unroll
        for (int m = 0; m < K_TOP; ++m) { v5[m] = -FLT_MAX; i5[m] = INT_MAX; }
        for (int j = 0; j < 8; ++j) {
            int src = t + 32 * j;
#pragma unroll
            for (int m = 0; m < K_TOP; ++m)
                insert5(sv[src * K_TOP + m], si[src * K_TOP + m], v5, i5);
        }
#pragma unroll
        for (int m = 0; m < K_TOP; ++m) { sv[t * K_TOP + m] = v5[m]; si[t * K_TOP + m] = i5[m]; }
    }
    __syncthreads();
    if (t == 0) {
#pragma unroll
        for (int m = 0; m < K_TOP; ++m) { v5[m] = -FLT_MAX; i5[m] = INT_MAX; }
        for (int s = 0; s < 32; ++s)
#pragma unroll
            for (int m = 0; m < K_TOP; ++m)
                insert5(sv[s * K_TOP + m], si[s * K_TOP + m], v5, i5);
#pragma unroll
        for (int m = 0; m < K_TOP; ++m) fi[m] = i5[m];
    }
    __syncthreads();

    // gather knowledge_full rows, converted to float (ints < 30000: exact)
    for (int pos = t; pos < K_TOP * LK; pos += 256) {
        int m = pos >> 5, l = pos & 31;
        out[(qi * K_TOP + m) * LK + l] = (float)kf[(size_t)fi[m] * LK + l];
    }
    // gather embed rows
    const int EO = BQ * K_TOP * LK;  // 10240
    for (int m = 0; m < K_TOP; ++m) {
        const float4* src = (const float4*)(ke + (size_t)fi[m] * DD);
        float4* dst = (float4*)(out + EO + (size_t)(qi * K_TOP + m) * DD);
        for (int pos = t; pos < DD / 4; pos += 256) dst[pos] = src[pos];
    }
}

extern "C" void kernel_launch(void* const* d_in, const int* in_sizes, int n_in,
                              void* d_out, int out_size, void* d_ws, size_t ws_size,
                              hipStream_t stream) {
    const float* query = (const float*)d_in[0];
    const float* ke    = (const float*)d_in[1];
    const int*   kf    = (const int*)d_in[2];
    float* out  = (float*)d_out;
    float* ws_f = (float*)d_ws;

    // ws layout (floats): qn[64] | pvals[NTILES*64*5] | pidx[NTILES*64*5]  (~4 MB)
    float* qn    = ws_f;
    float* pvals = ws_f + 64;
    int*   pidx  = (int*)(ws_f + 64 + (size_t)NTILES * BQ * K_TOP);

    qnorm_kernel<<<BQ, 256, 0, stream>>>(query, qn);
    sims_topk_kernel<<<NTILES, 256, 0, stream>>>(query, ke, qn, pvals, pidx);
    reduce_gather_kernel<<<BQ, 256, 0, stream>>>(pvals, pidx, ke, kf, out);
}